// Round 2
// baseline (961.885 us; speedup 1.0000x reference)
//
#include <hip/hip_runtime.h>

#define NTOK   25088          // B*P = 128*196
#define HIDD   768
#define NHEAD  12
#define HDIM   64
#define FFD    3072
#define NPAT   196

typedef __attribute__((ext_vector_type(8))) short short8;
typedef __attribute__((ext_vector_type(8))) __bf16 bf16x8;
typedef __attribute__((ext_vector_type(4))) float f32x4;
typedef __attribute__((ext_vector_type(4))) float fl4;
typedef __attribute__((ext_vector_type(4))) unsigned short us4;

#define AS1 __attribute__((address_space(1)))
#define AS3 __attribute__((address_space(3)))

__device__ __forceinline__ unsigned short f2bf(float f) {
  unsigned int u = __builtin_bit_cast(unsigned int, f);
  u += 0x7FFFu + ((u >> 16) & 1u);
  return (unsigned short)(u >> 16);
}
__device__ __forceinline__ float bf2f(unsigned short h) {
  unsigned int u = ((unsigned int)h) << 16;
  return __builtin_bit_cast(float, u);
}

// ---- MFMA wrapper: SFINAE over builtin operand type (short8 vs bf16x8) ----
template <typename A>
__device__ __forceinline__ auto mfma_sel(A a, A b, f32x4 c, int)
    -> decltype(__builtin_amdgcn_mfma_f32_16x16x32_bf16(a, b, c, 0, 0, 0)) {
  return __builtin_amdgcn_mfma_f32_16x16x32_bf16(a, b, c, 0, 0, 0);
}
template <typename A>
__device__ __forceinline__ auto mfma_sel(A a, A b, f32x4 c, long)
    -> decltype(__builtin_amdgcn_mfma_f32_16x16x32_bf16(
           __builtin_bit_cast(bf16x8, a), __builtin_bit_cast(bf16x8, b), c, 0, 0, 0)) {
  return __builtin_amdgcn_mfma_f32_16x16x32_bf16(
      __builtin_bit_cast(bf16x8, a), __builtin_bit_cast(bf16x8, b), c, 0, 0, 0);
}
__device__ __forceinline__ f32x4 MFMA16(short8 a, short8 b, f32x4 c) {
  return mfma_sel(a, b, c, 0);
}

__device__ __forceinline__ void gload16(const void* g, void* l) {
  __builtin_amdgcn_global_load_lds((const AS1 void*)g, (AS3 void*)l, 16, 0, 0);
}

// ---- build the 256x256 highpass operator, bf16, symmetric ----
__global__ __launch_bounds__(256) void build_M(unsigned short* __restrict__ Mb) {
  __shared__ float Cs[16], Ss[16];
  int t = threadIdx.x;
  if (t < 16) {
    float c = 0.f;
    for (int k = -4; k <= 3; ++k) c += cosf(0.39269908169872414f * (float)(k * t));
    Cs[t] = c;
    Ss[t] = -sinf(1.5707963267948966f * (float)t);
  }
  __syncthreads();
  int r = t >> 4, cc = t & 15;
  for (int j = 0; j < 256; ++j) {
    int dr = (r - (j >> 4)) & 15;
    int dc = (cc - (j & 15)) & 15;
    float val = ((t == j) ? 1.f : 0.f) - (Cs[dr] * Cs[dc] - Ss[dr] * Ss[dc]) * 0.00390625f;
    Mb[t * 256 + j] = f2bf(val);
  }
}

// ---- fp32 -> bf16 cast (element count multiple of 4) ----
__global__ __launch_bounds__(256) void castk(const float* __restrict__ s,
                                             unsigned short* __restrict__ d, long n4) {
  for (long i = (long)blockIdx.x * 256 + threadIdx.x; i < n4; i += (long)gridDim.x * 256) {
    fl4 v = *(const fl4*)(s + i * 4);
    us4 o;
    o[0] = f2bf(v[0]); o[1] = f2bf(v[1]); o[2] = f2bf(v[2]); o[3] = f2bf(v[3]);
    *(us4*)(d + i * 4) = o;
  }
}

// ---- bf16 GEMM, C = A(MxK) * B(NxK)^T, m97-style 128x128 tile, BK=32 ----
template <int OUT_BF16, int BIAS, int RELU>
__global__ __launch_bounds__(256) void gemm_bt(const unsigned short* __restrict__ A,
                                               const unsigned short* __restrict__ Bm,
                                               const float* __restrict__ bias,
                                               void* __restrict__ Cp,
                                               int Mdim, int Ndim, int Kdim) {
  __shared__ __align__(16) unsigned short As[128 * 32];
  __shared__ __align__(16) unsigned short Bs[128 * 32];
  const int nbn = Ndim >> 7;
  const int bm = blockIdx.x / nbn, bn = blockIdx.x % nbn;
  const int t = threadIdx.x;
  const int lane = t & 63;
  const int w = t >> 6;
  const int wr = (w >> 1) * 64, wc = (w & 1) * 64;
  const int lm = lane & 15, lk = (lane >> 4) * 8;

  f32x4 acc[4][4];
#pragma unroll
  for (int i = 0; i < 4; ++i)
#pragma unroll
    for (int j = 0; j < 4; ++j) acc[i][j] = (f32x4){0.f, 0.f, 0.f, 0.f};

  const unsigned short* Ab = A + (size_t)(bm * 128 + (t >> 2)) * Kdim + (t & 3) * 8;
  const unsigned short* Bb = Bm + (size_t)(bn * 128 + (t >> 2)) * Kdim + (t & 3) * 8;
  unsigned short* AsP = As + t * 8;
  unsigned short* BsP = Bs + t * 8;

  for (int k0 = 0; k0 < Kdim; k0 += 32) {
    gload16(Ab + k0, AsP);
    gload16(Ab + (size_t)64 * Kdim + k0, AsP + 2048);
    gload16(Bb + k0, BsP);
    gload16(Bb + (size_t)64 * Kdim + k0, BsP + 2048);
    asm volatile("s_waitcnt vmcnt(0)" ::: "memory");
    __syncthreads();
    short8 af[4], bfr[4];
#pragma unroll
    for (int mi = 0; mi < 4; ++mi) af[mi] = *(const short8*)&As[(wr + mi * 16 + lm) * 32 + lk];
#pragma unroll
    for (int ni = 0; ni < 4; ++ni) bfr[ni] = *(const short8*)&Bs[(wc + ni * 16 + lm) * 32 + lk];
#pragma unroll
    for (int mi = 0; mi < 4; ++mi)
#pragma unroll
      for (int ni = 0; ni < 4; ++ni) acc[mi][ni] = MFMA16(af[mi], bfr[ni], acc[mi][ni]);
    __syncthreads();
  }

  const int row0 = bm * 128 + wr + (lane >> 4) * 4;
  const int col0 = bn * 128 + wc + lm;
#pragma unroll
  for (int mi = 0; mi < 4; ++mi) {
#pragma unroll
    for (int ni = 0; ni < 4; ++ni) {
      int col = col0 + ni * 16;
      float bia = BIAS ? bias[col] : 0.f;
#pragma unroll
      for (int rg = 0; rg < 4; ++rg) {
        int row = row0 + mi * 16 + rg;
        float vv = acc[mi][ni][rg] + bia;
        if (RELU) vv = vv > 0.f ? vv : 0.f;
        if (OUT_BF16)
          ((unsigned short*)Cp)[(size_t)row * Ndim + col] = f2bf(vv);
        else
          ((float*)Cp)[(size_t)row * Ndim + col] = vv;
      }
    }
  }
}

// ---- LN kernels: one wave per 768-wide row, 4 rows per block ----
// ln0: bf16 in -> bf16 out (pure LN)
__global__ __launch_bounds__(256) void ln0_k(const unsigned short* __restrict__ x,
                                             const float* __restrict__ g,
                                             const float* __restrict__ bb,
                                             unsigned short* __restrict__ out) {
  int w = threadIdx.x >> 6, lane = threadIdx.x & 63;
  long row = (long)blockIdx.x * 4 + w;
  const unsigned short* xr = x + row * HIDD;
  float xv[12];
  float s1 = 0.f, s2 = 0.f;
#pragma unroll
  for (int c = 0; c < 3; ++c) {
    us4 u = *(const us4*)(xr + c * 256 + lane * 4);
#pragma unroll
    for (int j = 0; j < 4; ++j) {
      float f = bf2f(u[j]);
      xv[c * 4 + j] = f; s1 += f; s2 += f * f;
    }
  }
#pragma unroll
  for (int off = 32; off; off >>= 1) { s1 += __shfl_xor(s1, off); s2 += __shfl_xor(s2, off); }
  float m = s1 * (1.f / 768.f);
  float rs = rsqrtf(s2 * (1.f / 768.f) - m * m + 1e-5f);
#pragma unroll
  for (int c = 0; c < 3; ++c) {
    int cb = c * 256 + lane * 4;
    us4 o;
#pragma unroll
    for (int j = 0; j < 4; ++j) o[j] = f2bf((xv[c * 4 + j] - m) * rs * g[cb + j] + bb[cb + j]);
    *(us4*)(out + row * HIDD + cb) = o;
  }
}

// ln1: h2 = hp(bf16) + LN(ctx bf16); writes h2 fp32 + h2 bf16
__global__ __launch_bounds__(256) void ln1_k(const unsigned short* __restrict__ ctx,
                                             const unsigned short* __restrict__ hp,
                                             const float* __restrict__ g,
                                             const float* __restrict__ bb,
                                             float* __restrict__ h2f,
                                             unsigned short* __restrict__ h2b) {
  int w = threadIdx.x >> 6, lane = threadIdx.x & 63;
  long row = (long)blockIdx.x * 4 + w;
  const unsigned short* xr = ctx + row * HIDD;
  float xv[12];
  float s1 = 0.f, s2 = 0.f;
#pragma unroll
  for (int c = 0; c < 3; ++c) {
    us4 u = *(const us4*)(xr + c * 256 + lane * 4);
#pragma unroll
    for (int j = 0; j < 4; ++j) {
      float f = bf2f(u[j]);
      xv[c * 4 + j] = f; s1 += f; s2 += f * f;
    }
  }
#pragma unroll
  for (int off = 32; off; off >>= 1) { s1 += __shfl_xor(s1, off); s2 += __shfl_xor(s2, off); }
  float m = s1 * (1.f / 768.f);
  float rs = rsqrtf(s2 * (1.f / 768.f) - m * m + 1e-5f);
#pragma unroll
  for (int c = 0; c < 3; ++c) {
    int cb = c * 256 + lane * 4;
    us4 hv = *(const us4*)(hp + row * HIDD + cb);
    fl4 o;
    us4 ob;
#pragma unroll
    for (int j = 0; j < 4; ++j) {
      float y = bf2f(hv[j]) + (xv[c * 4 + j] - m) * rs * g[cb + j] + bb[cb + j];
      o[j] = y; ob[j] = f2bf(y);
    }
    *(fl4*)(h2f + row * HIDD + cb) = o;
    *(us4*)(h2b + row * HIDD + cb) = ob;
  }
}

// ln2: out = h2f + LN(mlp2); mlp2 lives in d_out, in-place per-row
__global__ __launch_bounds__(256) void ln2_k(float* __restrict__ mlp2_out,
                                             const float* __restrict__ h2f,
                                             const float* __restrict__ g,
                                             const float* __restrict__ bb) {
  int w = threadIdx.x >> 6, lane = threadIdx.x & 63;
  long row = (long)blockIdx.x * 4 + w;
  float* xr = mlp2_out + row * HIDD;
  fl4 v[3];
  float s1 = 0.f, s2 = 0.f;
#pragma unroll
  for (int c = 0; c < 3; ++c) {
    v[c] = *(const fl4*)(xr + c * 256 + lane * 4);
#pragma unroll
    for (int j = 0; j < 4; ++j) { s1 += v[c][j]; s2 += v[c][j] * v[c][j]; }
  }
#pragma unroll
  for (int off = 32; off; off >>= 1) { s1 += __shfl_xor(s1, off); s2 += __shfl_xor(s2, off); }
  float m = s1 * (1.f / 768.f);
  float rs = rsqrtf(s2 * (1.f / 768.f) - m * m + 1e-5f);
#pragma unroll
  for (int c = 0; c < 3; ++c) {
    int cb = c * 256 + lane * 4;
    fl4 hv = *(const fl4*)(h2f + row * HIDD + cb);
    fl4 o;
#pragma unroll
    for (int j = 0; j < 4; ++j) o[j] = hv[j] + (v[c][j] - m) * rs * g[cb + j] + bb[cb + j];
    *(fl4*)(xr + cb) = o;
  }
}

// ---- fused attention: one block per (b, head), 4 waves loop over 13 q-tiles ----
__global__ __launch_bounds__(256) void attn_k(const unsigned short* __restrict__ q,
                                              const unsigned short* __restrict__ k,
                                              const unsigned short* __restrict__ v,
                                              unsigned short* __restrict__ ctx) {
  __shared__ __align__(16) unsigned short VT[64 * 224];       // V^T, padded keys
  __shared__ __align__(16) unsigned short PL[4 * 16 * 224];   // per-wave P tile
  const int b = blockIdx.x / NHEAD, h = blockIdx.x % NHEAD;
  const int t = threadIdx.x, lane = t & 63, w = t >> 6;
  const size_t base = ((size_t)b * NPAT) * HIDD + h * HDIM;

  for (int idx = t; idx < NPAT * 64; idx += 256) {
    int p = idx >> 6, d = idx & 63;
    VT[d * 224 + p] = v[base + (size_t)p * HIDD + d];
  }
  for (int idx = t; idx < 28 * 64; idx += 256) {
    int p = NPAT + (idx >> 6), d = idx & 63;
    VT[d * 224 + p] = 0;
  }
  for (int idx = t; idx < 4 * 16 * 224; idx += 256) PL[idx] = 0;
  __syncthreads();

  unsigned short* plw = PL + w * 16 * 224;
  const int lm = lane & 15, lg = lane >> 4, lk = lg * 8;

  for (int qt = w; qt < 13; qt += 4) {
    const int q0 = qt * 16;
    int qrow = q0 + lm; if (qrow > NPAT - 1) qrow = NPAT - 1;
    short8 af0 = *(const short8*)&q[base + (size_t)qrow * HIDD + lk];
    short8 af1 = *(const short8*)&q[base + (size_t)qrow * HIDD + 32 + lk];

    f32x4 sc[13];
#pragma unroll
    for (int kt = 0; kt < 13; ++kt) {
      int krow = kt * 16 + lm; if (krow > NPAT - 1) krow = NPAT - 1;
      short8 b0 = *(const short8*)&k[base + (size_t)krow * HIDD + lk];
      short8 b1 = *(const short8*)&k[base + (size_t)krow * HIDD + 32 + lk];
      f32x4 z = (f32x4){0.f, 0.f, 0.f, 0.f};
      z = MFMA16(af0, b0, z);
      sc[kt] = MFMA16(af1, b1, z);
    }
#pragma unroll
    for (int kt = 0; kt < 13; ++kt) {
      int col = kt * 16 + lm;
#pragma unroll
      for (int rg = 0; rg < 4; ++rg) {
        float s = sc[kt][rg] * 0.125f;
        sc[kt][rg] = (col < NPAT) ? s : -1e30f;
      }
    }
    float inv[4];
#pragma unroll
    for (int rg = 0; rg < 4; ++rg) {
      float m = -1e30f;
#pragma unroll
      for (int kt = 0; kt < 13; ++kt) m = fmaxf(m, sc[kt][rg]);
      m = fmaxf(m, __shfl_xor(m, 1)); m = fmaxf(m, __shfl_xor(m, 2));
      m = fmaxf(m, __shfl_xor(m, 4)); m = fmaxf(m, __shfl_xor(m, 8));
      float s = 0.f;
#pragma unroll
      for (int kt = 0; kt < 13; ++kt) { float e = __expf(sc[kt][rg] - m); sc[kt][rg] = e; s += e; }
      s += __shfl_xor(s, 1); s += __shfl_xor(s, 2); s += __shfl_xor(s, 4); s += __shfl_xor(s, 8);
      inv[rg] = 1.f / s;
    }
#pragma unroll
    for (int kt = 0; kt < 13; ++kt) {
      int col = kt * 16 + lm;
#pragma unroll
      for (int rg = 0; rg < 4; ++rg)
        plw[(lg * 4 + rg) * 224 + col] = f2bf(sc[kt][rg] * inv[rg]);
    }
    asm volatile("s_waitcnt lgkmcnt(0)" ::: "memory");
    __builtin_amdgcn_sched_barrier(0);

    f32x4 oacc[4];
#pragma unroll
    for (int ni = 0; ni < 4; ++ni) oacc[ni] = (f32x4){0.f, 0.f, 0.f, 0.f};
#pragma unroll
    for (int kc = 0; kc < 7; ++kc) {
      short8 pa = *(const short8*)&plw[lm * 224 + kc * 32 + lk];
#pragma unroll
      for (int ni = 0; ni < 4; ++ni) {
        short8 bv = *(const short8*)&VT[(ni * 16 + lm) * 224 + kc * 32 + lk];
        oacc[ni] = MFMA16(pa, bv, oacc[ni]);
      }
    }
#pragma unroll
    for (int rg = 0; rg < 4; ++rg) {
      int r = q0 + lg * 4 + rg;
      if (r < NPAT) {
#pragma unroll
        for (int ni = 0; ni < 4; ++ni)
          ctx[base + (size_t)r * HIDD + ni * 16 + lm] = f2bf(oacc[ni][rg]);
      }
    }
  }
}

extern "C" void kernel_launch(void* const* d_in, const int* in_sizes, int n_in,
                              void* d_out, int out_size, void* d_ws, size_t ws_size,
                              hipStream_t stream) {
  const float* x    = (const float*)d_in[0];
  const float* q_w  = (const float*)d_in[1];
  const float* q_b  = (const float*)d_in[2];
  const float* k_w  = (const float*)d_in[3];
  const float* k_b  = (const float*)d_in[4];
  const float* v_w  = (const float*)d_in[5];
  const float* v_b  = (const float*)d_in[6];
  const float* w1   = (const float*)d_in[7];
  const float* b1   = (const float*)d_in[8];
  const float* w2   = (const float*)d_in[9];
  const float* b2   = (const float*)d_in[10];
  const float* ln0g = (const float*)d_in[11];
  const float* ln0b = (const float*)d_in[12];
  const float* ln1g = (const float*)d_in[13];
  const float* ln1b = (const float*)d_in[14];
  const float* ln2g = (const float*)d_in[15];
  const float* ln2b = (const float*)d_in[16];

  char* ws = (char*)d_ws;
  size_t o = 0;
  auto alloc = [&](size_t bytes) { size_t r = o; o += (bytes + 255) & ~(size_t)255; return r; };

  const size_t RSZ = (size_t)NTOK * HIDD * 2;   // 38,535,168 B per region
  unsigned short* Mb  = (unsigned short*)(ws + alloc(256 * 256 * 2));
  unsigned short* wqb = (unsigned short*)(ws + alloc((size_t)HIDD * HIDD * 2));
  unsigned short* wkb = (unsigned short*)(ws + alloc((size_t)HIDD * HIDD * 2));
  unsigned short* wvb = (unsigned short*)(ws + alloc((size_t)HIDD * HIDD * 2));
  unsigned short* w1b = (unsigned short*)(ws + alloc((size_t)FFD * HIDD * 2));
  unsigned short* w2b = (unsigned short*)(ws + alloc((size_t)HIDD * FFD * 2));
  char* r0 = ws + alloc(RSZ);   // x bf16 -> ctx bf16
  char* r1 = ws + alloc(RSZ);   // hp bf16
  char* r2 = ws + alloc(RSZ);   // hb (ln0 out) -> h2 bf16
  char* r3 = ws + alloc(RSZ);   // q -> mlp1 chunk
  char* r4 = ws + alloc(RSZ);   // k -> h2 fp32 (low half)
  char* r5 = ws + alloc(RSZ);   // v -> h2 fp32 (high half); r4+r5 contiguous
  (void)r5; (void)n_in; (void)in_sizes; (void)ws_size;

  unsigned short* xb  = (unsigned short*)r0;
  unsigned short* hpb = (unsigned short*)r1;
  unsigned short* hb  = (unsigned short*)r2;
  unsigned short* qb_ = (unsigned short*)r3;
  unsigned short* kb_ = (unsigned short*)r4;
  unsigned short* vb_ = (unsigned short*)r5;
  unsigned short* cxb = (unsigned short*)r0;   // ctx (x dead after highpass)
  float*          h2f = (float*)r4;            // 77MB spans r4+r5 (k,v dead after attn)
  unsigned short* h2b = (unsigned short*)r2;   // hb dead after QKV
  unsigned short* m1b = (unsigned short*)r3;   // mlp1 chunk (q dead after attn)
  float*          m2f = (float*)d_out;         // mlp2 fp32 straight into d_out

  build_M<<<1, 256, 0, stream>>>(Mb);

  auto cgrid = [](long n4) { long g = (n4 + 255) / 256; return (int)(g > 2048 ? 2048 : g); };
  long nx4 = (long)NTOK * HIDD / 4;
  castk<<<cgrid(nx4), 256, 0, stream>>>(x, xb, nx4);
  long nw4 = (long)HIDD * HIDD / 4;
  castk<<<cgrid(nw4), 256, 0, stream>>>(q_w, wqb, nw4);
  castk<<<cgrid(nw4), 256, 0, stream>>>(k_w, wkb, nw4);
  castk<<<cgrid(nw4), 256, 0, stream>>>(v_w, wvb, nw4);
  long nf4 = (long)FFD * HIDD / 4;
  castk<<<cgrid(nf4), 256, 0, stream>>>(w1, w1b, nf4);
  castk<<<cgrid(nf4), 256, 0, stream>>>(w2, w2b, nf4);

  // highpass: (75264 x 256) @ M(256 x 256)^T -> hp bf16
  gemm_bt<1, 0, 0><<<588 * 2, 256, 0, stream>>>(xb, Mb, nullptr, hpb, 75264, 256, 256);
  ln0_k<<<NTOK / 4, 256, 0, stream>>>(hpb, ln0g, ln0b, hb);

  gemm_bt<1, 1, 0><<<196 * 6, 256, 0, stream>>>(hb, wqb, q_b, qb_, NTOK, HIDD, HIDD);
  gemm_bt<1, 1, 0><<<196 * 6, 256, 0, stream>>>(hb, wkb, k_b, kb_, NTOK, HIDD, HIDD);
  gemm_bt<1, 1, 0><<<196 * 6, 256, 0, stream>>>(hb, wvb, v_b, vb_, NTOK, HIDD, HIDD);

  attn_k<<<128 * NHEAD, 256, 0, stream>>>(qb_, kb_, vb_, cxb);

  ln1_k<<<NTOK / 4, 256, 0, stream>>>(cxb, hpb, ln1g, ln1b, h2f, h2b);

  // MLP in 4 token-chunks of 6272 (=49*128) to keep mlp1 inside one region
  for (int ch = 0; ch < 4; ++ch) {
    const unsigned short* h2c = h2b + (size_t)ch * 6272 * HIDD;
    float* m2c = m2f + (size_t)ch * 6272 * HIDD;
    gemm_bt<1, 1, 1><<<49 * 24, 256, 0, stream>>>(h2c, w1b, b1, m1b, 6272, FFD, HIDD);
    gemm_bt<0, 1, 0><<<49 * 6, 256, 0, stream>>>(m1b, w2b, b2, m2c, 6272, HIDD, FFD);
  }

  // final: d_out = h2f + LN(d_out), in-place per row
  ln2_k<<<NTOK / 4, 256, 0, stream>>>(m2f, h2f, ln2g, ln2b);
  (void)out_size;
}

// Round 3
// 874.248 us; speedup vs baseline: 1.1002x; 1.1002x over previous
//
#include <hip/hip_runtime.h>

#define NTOK   25088          // B*P = 128*196
#define HIDD   768
#define NHEAD  12
#define HDIM   64
#define FFD    3072
#define NPAT   196

typedef __attribute__((ext_vector_type(8))) short short8;
typedef __attribute__((ext_vector_type(8))) __bf16 bf16x8;
typedef __attribute__((ext_vector_type(4))) float f32x4;
typedef __attribute__((ext_vector_type(4))) float fl4;
typedef __attribute__((ext_vector_type(4))) unsigned short us4;

#define AS1 __attribute__((address_space(1)))
#define AS3 __attribute__((address_space(3)))

__device__ __forceinline__ unsigned short f2bf(float f) {
  unsigned int u = __builtin_bit_cast(unsigned int, f);
  u += 0x7FFFu + ((u >> 16) & 1u);
  return (unsigned short)(u >> 16);
}
__device__ __forceinline__ float bf2f(unsigned short h) {
  unsigned int u = ((unsigned int)h) << 16;
  return __builtin_bit_cast(float, u);
}

// ---- MFMA wrapper: SFINAE over builtin operand type (short8 vs bf16x8) ----
template <typename A>
__device__ __forceinline__ auto mfma_sel(A a, A b, f32x4 c, int)
    -> decltype(__builtin_amdgcn_mfma_f32_16x16x32_bf16(a, b, c, 0, 0, 0)) {
  return __builtin_amdgcn_mfma_f32_16x16x32_bf16(a, b, c, 0, 0, 0);
}
template <typename A>
__device__ __forceinline__ auto mfma_sel(A a, A b, f32x4 c, long)
    -> decltype(__builtin_amdgcn_mfma_f32_16x16x32_bf16(
           __builtin_bit_cast(bf16x8, a), __builtin_bit_cast(bf16x8, b), c, 0, 0, 0)) {
  return __builtin_amdgcn_mfma_f32_16x16x32_bf16(
      __builtin_bit_cast(bf16x8, a), __builtin_bit_cast(bf16x8, b), c, 0, 0, 0);
}
__device__ __forceinline__ f32x4 MFMA16(short8 a, short8 b, f32x4 c) {
  return mfma_sel(a, b, c, 0);
}

__device__ __forceinline__ void gload16(const void* g, void* l) {
  __builtin_amdgcn_global_load_lds((const AS1 void*)g, (AS3 void*)l, 16, 0, 0);
}

// ---- build the 256x256 highpass operator, bf16, symmetric ----
__global__ __launch_bounds__(256) void build_M(unsigned short* __restrict__ Mb) {
  __shared__ float Cs[16], Ss[16];
  int t = threadIdx.x;
  if (t < 16) {
    float c = 0.f;
    for (int k = -4; k <= 3; ++k) c += cosf(0.39269908169872414f * (float)(k * t));
    Cs[t] = c;
    Ss[t] = -sinf(1.5707963267948966f * (float)t);
  }
  __syncthreads();
  int r = t >> 4, cc = t & 15;
  for (int j = 0; j < 256; ++j) {
    int dr = (r - (j >> 4)) & 15;
    int dc = (cc - (j & 15)) & 15;
    float val = ((t == j) ? 1.f : 0.f) - (Cs[dr] * Cs[dc] - Ss[dr] * Ss[dc]) * 0.00390625f;
    Mb[t * 256 + j] = f2bf(val);
  }
}

// ---- fp32 -> bf16 cast (element count multiple of 4) ----
__global__ __launch_bounds__(256) void castk(const float* __restrict__ s,
                                             unsigned short* __restrict__ d, long n4) {
  for (long i = (long)blockIdx.x * 256 + threadIdx.x; i < n4; i += (long)gridDim.x * 256) {
    fl4 v = *(const fl4*)(s + i * 4);
    us4 o;
    o[0] = f2bf(v[0]); o[1] = f2bf(v[1]); o[2] = f2bf(v[2]); o[3] = f2bf(v[3]);
    *(us4*)(d + i * 4) = o;
  }
}

// ---- bf16 GEMM, C = A(MxK) * B(NxK)^T, m97-style 128x128 tile, BK=32 ----
template <int OUT_BF16, int BIAS, int RELU>
__global__ __launch_bounds__(256) void gemm_bt(const unsigned short* __restrict__ A,
                                               const unsigned short* __restrict__ Bm,
                                               const float* __restrict__ bias,
                                               void* __restrict__ Cp,
                                               int Mdim, int Ndim, int Kdim) {
  __shared__ __align__(16) unsigned short As[128 * 32];
  __shared__ __align__(16) unsigned short Bs[128 * 32];
  const int nbn = Ndim >> 7;
  const int bm = blockIdx.x / nbn, bn = blockIdx.x % nbn;
  const int t = threadIdx.x;
  const int lane = t & 63;
  const int w = t >> 6;
  const int wr = (w >> 1) * 64, wc = (w & 1) * 64;
  const int lm = lane & 15, lk = (lane >> 4) * 8;

  f32x4 acc[4][4];
#pragma unroll
  for (int i = 0; i < 4; ++i)
#pragma unroll
    for (int j = 0; j < 4; ++j) acc[i][j] = (f32x4){0.f, 0.f, 0.f, 0.f};

  const unsigned short* Ab = A + (size_t)(bm * 128 + (t >> 2)) * Kdim + (t & 3) * 8;
  const unsigned short* Bb = Bm + (size_t)(bn * 128 + (t >> 2)) * Kdim + (t & 3) * 8;
  unsigned short* AsP = As + t * 8;
  unsigned short* BsP = Bs + t * 8;

  for (int k0 = 0; k0 < Kdim; k0 += 32) {
    gload16(Ab + k0, AsP);
    gload16(Ab + (size_t)64 * Kdim + k0, AsP + 2048);
    gload16(Bb + k0, BsP);
    gload16(Bb + (size_t)64 * Kdim + k0, BsP + 2048);
    asm volatile("s_waitcnt vmcnt(0)" ::: "memory");
    __syncthreads();
    short8 af[4], bfr[4];
#pragma unroll
    for (int mi = 0; mi < 4; ++mi) af[mi] = *(const short8*)&As[(wr + mi * 16 + lm) * 32 + lk];
#pragma unroll
    for (int ni = 0; ni < 4; ++ni) bfr[ni] = *(const short8*)&Bs[(wc + ni * 16 + lm) * 32 + lk];
#pragma unroll
    for (int mi = 0; mi < 4; ++mi)
#pragma unroll
      for (int ni = 0; ni < 4; ++ni) acc[mi][ni] = MFMA16(af[mi], bfr[ni], acc[mi][ni]);
    __syncthreads();
  }

  const int row0 = bm * 128 + wr + (lane >> 4) * 4;
  const int col0 = bn * 128 + wc + lm;
#pragma unroll
  for (int mi = 0; mi < 4; ++mi) {
#pragma unroll
    for (int ni = 0; ni < 4; ++ni) {
      int col = col0 + ni * 16;
      float bia = BIAS ? bias[col] : 0.f;
#pragma unroll
      for (int rg = 0; rg < 4; ++rg) {
        int row = row0 + mi * 16 + rg;
        float vv = acc[mi][ni][rg] + bia;
        if (RELU) vv = vv > 0.f ? vv : 0.f;
        if (OUT_BF16)
          ((unsigned short*)Cp)[(size_t)row * Ndim + col] = f2bf(vv);
        else
          ((float*)Cp)[(size_t)row * Ndim + col] = vv;
      }
    }
  }
}

// ---- LN kernels: one wave per 768-wide row, 4 rows per block ----
__global__ __launch_bounds__(256) void ln0_k(const unsigned short* __restrict__ x,
                                             const float* __restrict__ g,
                                             const float* __restrict__ bb,
                                             unsigned short* __restrict__ out) {
  int w = threadIdx.x >> 6, lane = threadIdx.x & 63;
  long row = (long)blockIdx.x * 4 + w;
  const unsigned short* xr = x + row * HIDD;
  float xv[12];
  float s1 = 0.f, s2 = 0.f;
#pragma unroll
  for (int c = 0; c < 3; ++c) {
    us4 u = *(const us4*)(xr + c * 256 + lane * 4);
#pragma unroll
    for (int j = 0; j < 4; ++j) {
      float f = bf2f(u[j]);
      xv[c * 4 + j] = f; s1 += f; s2 += f * f;
    }
  }
#pragma unroll
  for (int off = 32; off; off >>= 1) { s1 += __shfl_xor(s1, off); s2 += __shfl_xor(s2, off); }
  float m = s1 * (1.f / 768.f);
  float rs = rsqrtf(s2 * (1.f / 768.f) - m * m + 1e-5f);
#pragma unroll
  for (int c = 0; c < 3; ++c) {
    int cb = c * 256 + lane * 4;
    us4 o;
#pragma unroll
    for (int j = 0; j < 4; ++j) o[j] = f2bf((xv[c * 4 + j] - m) * rs * g[cb + j] + bb[cb + j]);
    *(us4*)(out + row * HIDD + cb) = o;
  }
}

// ln1: h2 = hp(bf16) + LN(ctx bf16); writes h2 fp32 + h2 bf16
__global__ __launch_bounds__(256) void ln1_k(const unsigned short* __restrict__ ctx,
                                             const unsigned short* __restrict__ hp,
                                             const float* __restrict__ g,
                                             const float* __restrict__ bb,
                                             float* __restrict__ h2f,
                                             unsigned short* __restrict__ h2b) {
  int w = threadIdx.x >> 6, lane = threadIdx.x & 63;
  long row = (long)blockIdx.x * 4 + w;
  const unsigned short* xr = ctx + row * HIDD;
  float xv[12];
  float s1 = 0.f, s2 = 0.f;
#pragma unroll
  for (int c = 0; c < 3; ++c) {
    us4 u = *(const us4*)(xr + c * 256 + lane * 4);
#pragma unroll
    for (int j = 0; j < 4; ++j) {
      float f = bf2f(u[j]);
      xv[c * 4 + j] = f; s1 += f; s2 += f * f;
    }
  }
#pragma unroll
  for (int off = 32; off; off >>= 1) { s1 += __shfl_xor(s1, off); s2 += __shfl_xor(s2, off); }
  float m = s1 * (1.f / 768.f);
  float rs = rsqrtf(s2 * (1.f / 768.f) - m * m + 1e-5f);
#pragma unroll
  for (int c = 0; c < 3; ++c) {
    int cb = c * 256 + lane * 4;
    us4 hv = *(const us4*)(hp + row * HIDD + cb);
    fl4 o;
    us4 ob;
#pragma unroll
    for (int j = 0; j < 4; ++j) {
      float y = bf2f(hv[j]) + (xv[c * 4 + j] - m) * rs * g[cb + j] + bb[cb + j];
      o[j] = y; ob[j] = f2bf(y);
    }
    *(fl4*)(h2f + row * HIDD + cb) = o;
    *(us4*)(h2b + row * HIDD + cb) = ob;
  }
}

// ln2: out = h2f + LN(mlp2); mlp2 lives in d_out, in-place per-row
__global__ __launch_bounds__(256) void ln2_k(float* __restrict__ mlp2_out,
                                             const float* __restrict__ h2f,
                                             const float* __restrict__ g,
                                             const float* __restrict__ bb) {
  int w = threadIdx.x >> 6, lane = threadIdx.x & 63;
  long row = (long)blockIdx.x * 4 + w;
  float* xr = mlp2_out + row * HIDD;
  fl4 v[3];
  float s1 = 0.f, s2 = 0.f;
#pragma unroll
  for (int c = 0; c < 3; ++c) {
    v[c] = *(const fl4*)(xr + c * 256 + lane * 4);
#pragma unroll
    for (int j = 0; j < 4; ++j) { s1 += v[c][j]; s2 += v[c][j] * v[c][j]; }
  }
#pragma unroll
  for (int off = 32; off; off >>= 1) { s1 += __shfl_xor(s1, off); s2 += __shfl_xor(s2, off); }
  float m = s1 * (1.f / 768.f);
  float rs = rsqrtf(s2 * (1.f / 768.f) - m * m + 1e-5f);
#pragma unroll
  for (int c = 0; c < 3; ++c) {
    int cb = c * 256 + lane * 4;
    fl4 hv = *(const fl4*)(h2f + row * HIDD + cb);
    fl4 o;
#pragma unroll
    for (int j = 0; j < 4; ++j) o[j] = hv[j] + (v[c][j] - m) * rs * g[cb + j] + bb[cb + j];
    *(fl4*)(xr + cb) = o;
  }
}

// ---- fused attention: one block per (b, head), 4 waves loop over 13 q-tiles ----
// LDS: VT 64x232 (29.7KB, 2-way max conflicts) + per-wave 16x40 P-chunk (5KB).
__global__ __launch_bounds__(256, 4) void attn_k(const unsigned short* __restrict__ q,
                                                 const unsigned short* __restrict__ k,
                                                 const unsigned short* __restrict__ v,
                                                 unsigned short* __restrict__ ctx) {
  __shared__ __align__(16) unsigned short VT[64 * 232];     // V^T, stride 232
  __shared__ __align__(16) unsigned short PL[4][16 * 40];   // per-wave P chunk, stride 40
  const int b = blockIdx.x / NHEAD, h = blockIdx.x % NHEAD;
  const int t = threadIdx.x, lane = t & 63, w = t >> 6;
  const size_t base = ((size_t)b * NPAT) * HIDD + h * HDIM;

  // stage V^T: pack 2 consecutive patches per u32 write
  for (int idx = t; idx < 98 * 64; idx += 256) {
    int pp = idx >> 6, d = idx & 63;
    unsigned int val = (unsigned int)v[base + (size_t)(2 * pp) * HIDD + d]
                     | ((unsigned int)v[base + (size_t)(2 * pp + 1) * HIDD + d] << 16);
    *(unsigned int*)&VT[d * 232 + 2 * pp] = val;
  }
  // zero pad patches 196..231
  for (int idx = t; idx < 64 * 18; idx += 256) {
    int d = idx / 18, c = idx % 18;
    *(unsigned int*)&VT[d * 232 + 196 + 2 * c] = 0;
  }
  __syncthreads();

  unsigned short* plw = (unsigned short*)PL[w];
  const int lm = lane & 15, lg = lane >> 4, lk = lg * 8;

  for (int qt = w; qt < 13; qt += 4) {
    const int q0 = qt * 16;
    int qrow = q0 + lm; if (qrow > NPAT - 1) qrow = NPAT - 1;
    short8 af0 = *(const short8*)&q[base + (size_t)qrow * HIDD + lk];
    short8 af1 = *(const short8*)&q[base + (size_t)qrow * HIDD + 32 + lk];

    f32x4 sc[13];
#pragma unroll
    for (int kt = 0; kt < 13; ++kt) {
      int krow = kt * 16 + lm; if (krow > NPAT - 1) krow = NPAT - 1;
      short8 b0 = *(const short8*)&k[base + (size_t)krow * HIDD + lk];
      short8 b1 = *(const short8*)&k[base + (size_t)krow * HIDD + 32 + lk];
      f32x4 z = (f32x4){0.f, 0.f, 0.f, 0.f};
      z = MFMA16(af0, b0, z);
      sc[kt] = MFMA16(af1, b1, z);
    }
#pragma unroll
    for (int kt = 0; kt < 13; ++kt) {
      int col = kt * 16 + lm;
#pragma unroll
      for (int rg = 0; rg < 4; ++rg) {
        float s = sc[kt][rg] * 0.125f;
        sc[kt][rg] = (col < NPAT) ? s : -1e30f;
      }
    }
    float inv[4];
#pragma unroll
    for (int rg = 0; rg < 4; ++rg) {
      float m = -1e30f;
#pragma unroll
      for (int kt = 0; kt < 13; ++kt) m = fmaxf(m, sc[kt][rg]);
      m = fmaxf(m, __shfl_xor(m, 1)); m = fmaxf(m, __shfl_xor(m, 2));
      m = fmaxf(m, __shfl_xor(m, 4)); m = fmaxf(m, __shfl_xor(m, 8));
      float s = 0.f;
#pragma unroll
      for (int kt = 0; kt < 13; ++kt) { float e = __expf(sc[kt][rg] - m); sc[kt][rg] = e; s += e; }
      s += __shfl_xor(s, 1); s += __shfl_xor(s, 2); s += __shfl_xor(s, 4); s += __shfl_xor(s, 8);
      inv[rg] = 1.f / s;
    }

    f32x4 oacc[4];
#pragma unroll
    for (int ni = 0; ni < 4; ++ni) oacc[ni] = (f32x4){0.f, 0.f, 0.f, 0.f};
#pragma unroll
    for (int kc = 0; kc < 7; ++kc) {
#pragma unroll
      for (int sub = 0; sub < 2; ++sub) {
        const int kt = 2 * kc + sub;
#pragma unroll
        for (int rg = 0; rg < 4; ++rg) {
          unsigned short pv_ = 0;
          if (kt < 13) pv_ = f2bf(sc[kt][rg] * inv[rg]);
          plw[(lg * 4 + rg) * 40 + sub * 16 + lm] = pv_;
        }
      }
      asm volatile("s_waitcnt lgkmcnt(0)" ::: "memory");
      __builtin_amdgcn_sched_barrier(0);
      short8 pa = *(const short8*)&plw[lm * 40 + lk];
#pragma unroll
      for (int ni = 0; ni < 4; ++ni) {
        short8 bv = *(const short8*)&VT[(ni * 16 + lm) * 232 + kc * 32 + lk];
        oacc[ni] = MFMA16(pa, bv, oacc[ni]);
      }
    }
#pragma unroll
    for (int rg = 0; rg < 4; ++rg) {
      int r = q0 + lg * 4 + rg;
      if (r < NPAT) {
#pragma unroll
        for (int ni = 0; ni < 4; ++ni)
          ctx[base + (size_t)r * HIDD + ni * 16 + lm] = f2bf(oacc[ni][rg]);
      }
    }
  }
}

extern "C" void kernel_launch(void* const* d_in, const int* in_sizes, int n_in,
                              void* d_out, int out_size, void* d_ws, size_t ws_size,
                              hipStream_t stream) {
  const float* x    = (const float*)d_in[0];
  const float* q_w  = (const float*)d_in[1];
  const float* q_b  = (const float*)d_in[2];
  const float* k_w  = (const float*)d_in[3];
  const float* k_b  = (const float*)d_in[4];
  const float* v_w  = (const float*)d_in[5];
  const float* v_b  = (const float*)d_in[6];
  const float* w1   = (const float*)d_in[7];
  const float* b1   = (const float*)d_in[8];
  const float* w2   = (const float*)d_in[9];
  const float* b2   = (const float*)d_in[10];
  const float* ln0g = (const float*)d_in[11];
  const float* ln0b = (const float*)d_in[12];
  const float* ln1g = (const float*)d_in[13];
  const float* ln1b = (const float*)d_in[14];
  const float* ln2g = (const float*)d_in[15];
  const float* ln2b = (const float*)d_in[16];

  char* ws = (char*)d_ws;
  size_t o = 0;
  auto alloc = [&](size_t bytes) { size_t r = o; o += (bytes + 255) & ~(size_t)255; return r; };

  const size_t RSZ = (size_t)NTOK * HIDD * 2;   // 38,535,168 B per region (256-aligned)
  unsigned short* Mb  = (unsigned short*)(ws + alloc(256 * 256 * 2));
  unsigned short* wqb = (unsigned short*)(ws + alloc((size_t)HIDD * HIDD * 2));
  unsigned short* wkb = (unsigned short*)(ws + alloc((size_t)HIDD * HIDD * 2));
  unsigned short* wvb = (unsigned short*)(ws + alloc((size_t)HIDD * HIDD * 2));
  unsigned short* w1b = (unsigned short*)(ws + alloc((size_t)FFD * HIDD * 2));
  unsigned short* w2b = (unsigned short*)(ws + alloc((size_t)HIDD * FFD * 2));
  char* r0 = ws + alloc(RSZ);   // x bf16 -> ctx -> mlp1 chunk (low half)
  char* r1 = ws + alloc(RSZ);   // hp bf16 -> mlp1 chunk (high half); r0+r1 contiguous
  char* r2 = ws + alloc(RSZ);   // hb (ln0 out) -> h2 bf16
  char* r3 = ws + alloc(RSZ);   // q
  char* r4 = ws + alloc(RSZ);   // k -> h2 fp32 (low half)
  char* r5 = ws + alloc(RSZ);   // v -> h2 fp32 (high half); r4+r5 contiguous
  (void)r5; (void)n_in; (void)in_sizes; (void)ws_size;

  unsigned short* xb  = (unsigned short*)r0;
  unsigned short* hpb = (unsigned short*)r1;
  unsigned short* hb  = (unsigned short*)r2;
  unsigned short* qb_ = (unsigned short*)r3;
  unsigned short* kb_ = (unsigned short*)r4;
  unsigned short* vb_ = (unsigned short*)r5;
  unsigned short* cxb = (unsigned short*)r0;   // ctx (x dead after highpass)
  float*          h2f = (float*)r4;            // 77MB spans r4+r5 (k,v dead after attn)
  unsigned short* h2b = (unsigned short*)r2;   // hb dead after QKV
  unsigned short* m1b = (unsigned short*)r0;   // mlp1 chunk spans r0+r1 exactly (77,070,336 B)
  float*          m2f = (float*)d_out;         // mlp2 fp32 straight into d_out

  build_M<<<1, 256, 0, stream>>>(Mb);

  auto cgrid = [](long n4) { long g = (n4 + 255) / 256; return (int)(g > 2048 ? 2048 : g); };
  long nx4 = (long)NTOK * HIDD / 4;
  castk<<<cgrid(nx4), 256, 0, stream>>>(x, xb, nx4);
  long nw4 = (long)HIDD * HIDD / 4;
  castk<<<cgrid(nw4), 256, 0, stream>>>(q_w, wqb, nw4);
  castk<<<cgrid(nw4), 256, 0, stream>>>(k_w, wkb, nw4);
  castk<<<cgrid(nw4), 256, 0, stream>>>(v_w, wvb, nw4);
  long nf4 = (long)FFD * HIDD / 4;
  castk<<<cgrid(nf4), 256, 0, stream>>>(w1, w1b, nf4);
  castk<<<cgrid(nf4), 256, 0, stream>>>(w2, w2b, nf4);

  // highpass: (75264 x 256) @ M(256 x 256)^T -> hp bf16
  gemm_bt<1, 0, 0><<<588 * 2, 256, 0, stream>>>(xb, Mb, nullptr, hpb, 75264, 256, 256);
  ln0_k<<<NTOK / 4, 256, 0, stream>>>(hpb, ln0g, ln0b, hb);

  gemm_bt<1, 1, 0><<<196 * 6, 256, 0, stream>>>(hb, wqb, q_b, qb_, NTOK, HIDD, HIDD);
  gemm_bt<1, 1, 0><<<196 * 6, 256, 0, stream>>>(hb, wkb, k_b, kb_, NTOK, HIDD, HIDD);
  gemm_bt<1, 1, 0><<<196 * 6, 256, 0, stream>>>(hb, wvb, v_b, vb_, NTOK, HIDD, HIDD);

  attn_k<<<128 * NHEAD, 256, 0, stream>>>(qb_, kb_, vb_, cxb);

  ln1_k<<<NTOK / 4, 256, 0, stream>>>(cxb, hpb, ln1g, ln1b, h2f, h2b);

  // MLP in 2 token-chunks of 12544 (=98*128); mlp1 chunk fills r0+r1 exactly
  for (int ch = 0; ch < 2; ++ch) {
    const unsigned short* h2c = h2b + (size_t)ch * 12544 * HIDD;
    float* m2c = m2f + (size_t)ch * 12544 * HIDD;
    gemm_bt<1, 1, 1><<<98 * 24, 256, 0, stream>>>(h2c, w1b, b1, m1b, 12544, FFD, HIDD);
    gemm_bt<0, 1, 0><<<98 * 6, 256, 0, stream>>>(m1b, w2b, b2, m2c, 12544, HIDD, FFD);
  }

  // final: d_out = h2f + LN(d_out), in-place per row
  ln2_k<<<NTOK / 4, 256, 0, stream>>>(m2f, h2f, ln2g, ln2b);
  (void)out_size;
}

// Round 5
// 761.414 us; speedup vs baseline: 1.2633x; 1.1482x over previous
//
#include <hip/hip_runtime.h>

#define NTOK   25088          // B*P = 128*196
#define HIDD   768
#define NHEAD  12
#define HDIM   64
#define FFD    3072
#define NPAT   196
#define QKVS   2304           // interleaved qkv row stride

typedef __attribute__((ext_vector_type(8))) short short8;
typedef __attribute__((ext_vector_type(8))) __bf16 bf16x8;
typedef __attribute__((ext_vector_type(4))) float f32x4;
typedef __attribute__((ext_vector_type(4))) float fl4;
typedef __attribute__((ext_vector_type(4))) unsigned short us4;
typedef __attribute__((ext_vector_type(8))) unsigned short us8;

#define AS1 __attribute__((address_space(1)))
#define AS3 __attribute__((address_space(3)))

__device__ __forceinline__ unsigned short f2bf(float f) {
  unsigned int u = __builtin_bit_cast(unsigned int, f);
  u += 0x7FFFu + ((u >> 16) & 1u);
  return (unsigned short)(u >> 16);
}
__device__ __forceinline__ float bf2f(unsigned short h) {
  unsigned int u = ((unsigned int)h) << 16;
  return __builtin_bit_cast(float, u);
}

// ---- MFMA wrapper: SFINAE over builtin operand type (short8 vs bf16x8) ----
template <typename A>
__device__ __forceinline__ auto mfma_sel(A a, A b, f32x4 c, int)
    -> decltype(__builtin_amdgcn_mfma_f32_16x16x32_bf16(a, b, c, 0, 0, 0)) {
  return __builtin_amdgcn_mfma_f32_16x16x32_bf16(a, b, c, 0, 0, 0);
}
template <typename A>
__device__ __forceinline__ auto mfma_sel(A a, A b, f32x4 c, long)
    -> decltype(__builtin_amdgcn_mfma_f32_16x16x32_bf16(
           __builtin_bit_cast(bf16x8, a), __builtin_bit_cast(bf16x8, b), c, 0, 0, 0)) {
  return __builtin_amdgcn_mfma_f32_16x16x32_bf16(
      __builtin_bit_cast(bf16x8, a), __builtin_bit_cast(bf16x8, b), c, 0, 0, 0);
}
__device__ __forceinline__ f32x4 MFMA16(short8 a, short8 b, f32x4 c) {
  return mfma_sel(a, b, c, 0);
}

__device__ __forceinline__ void gload16(const void* g, void* l) {
  __builtin_amdgcn_global_load_lds((const AS1 void*)g, (AS3 void*)l, 16, 0, 0);
}

// ---- build the 256x256 highpass operator, bf16, symmetric ----
__global__ __launch_bounds__(256) void build_M(unsigned short* __restrict__ Mb) {
  __shared__ float Cs[16], Ss[16];
  int t = threadIdx.x;
  if (t < 16) {
    float c = 0.f;
    for (int k = -4; k <= 3; ++k) c += cosf(0.39269908169872414f * (float)(k * t));
    Cs[t] = c;
    Ss[t] = -sinf(1.5707963267948966f * (float)t);
  }
  __syncthreads();
  int r = t >> 4, cc = t & 15;
  for (int j = 0; j < 256; ++j) {
    int dr = (r - (j >> 4)) & 15;
    int dc = (cc - (j & 15)) & 15;
    float val = ((t == j) ? 1.f : 0.f) - (Cs[dr] * Cs[dc] - Ss[dr] * Ss[dc]) * 0.00390625f;
    Mb[t * 256 + j] = f2bf(val);
  }
}

// ---- fp32 -> bf16 cast (element count multiple of 4) ----
__global__ __launch_bounds__(256) void castk(const float* __restrict__ s,
                                             unsigned short* __restrict__ d, long n4) {
  for (long i = (long)blockIdx.x * 256 + threadIdx.x; i < n4; i += (long)gridDim.x * 256) {
    fl4 v = *(const fl4*)(s + i * 4);
    us4 o;
    o[0] = f2bf(v[0]); o[1] = f2bf(v[1]); o[2] = f2bf(v[2]); o[3] = f2bf(v[3]);
    *(us4*)(d + i * 4) = o;
  }
}

// ---- concat q_b,k_b,v_b -> [2304] fp32 ----
__global__ __launch_bounds__(256) void bias_cat(const float* __restrict__ qb,
                                                const float* __restrict__ kb,
                                                const float* __restrict__ vb,
                                                float* __restrict__ d) {
  for (int i = threadIdx.x; i < QKVS; i += 256)
    d[i] = (i < 768) ? qb[i] : (i < 1536) ? kb[i - 768] : vb[i - 1536];
}

// ---- bf16 GEMM, C = A(MxK) * B(NxK)^T, m97-style 128x128 tile, BK=32 ----
template <int OUT_BF16, int BIAS, int RELU>
__global__ __launch_bounds__(256) void gemm_bt(const unsigned short* __restrict__ A,
                                               const unsigned short* __restrict__ Bm,
                                               const float* __restrict__ bias,
                                               void* __restrict__ Cp,
                                               int Mdim, int Ndim, int Kdim) {
  __shared__ __align__(16) unsigned short As[128 * 32];
  __shared__ __align__(16) unsigned short Bs[128 * 32];
  const int nbn = Ndim >> 7;
  const int bm = blockIdx.x / nbn, bn = blockIdx.x % nbn;
  const int t = threadIdx.x;
  const int lane = t & 63;
  const int w = t >> 6;
  const int wr = (w >> 1) * 64, wc = (w & 1) * 64;
  const int lm = lane & 15, lk = (lane >> 4) * 8;

  f32x4 acc[4][4];
#pragma unroll
  for (int i = 0; i < 4; ++i)
#pragma unroll
    for (int j = 0; j < 4; ++j) acc[i][j] = (f32x4){0.f, 0.f, 0.f, 0.f};

  const unsigned short* Ab = A + (size_t)(bm * 128 + (t >> 2)) * Kdim + (t & 3) * 8;
  const unsigned short* Bb = Bm + (size_t)(bn * 128 + (t >> 2)) * Kdim + (t & 3) * 8;
  unsigned short* AsP = As + t * 8;
  unsigned short* BsP = Bs + t * 8;

  for (int k0 = 0; k0 < Kdim; k0 += 32) {
    gload16(Ab + k0, AsP);
    gload16(Ab + (size_t)64 * Kdim + k0, AsP + 2048);
    gload16(Bb + k0, BsP);
    gload16(Bb + (size_t)64 * Kdim + k0, BsP + 2048);
    asm volatile("s_waitcnt vmcnt(0)" ::: "memory");
    __syncthreads();
    short8 af[4], bfr[4];
#pragma unroll
    for (int mi = 0; mi < 4; ++mi) af[mi] = *(const short8*)&As[(wr + mi * 16 + lm) * 32 + lk];
#pragma unroll
    for (int ni = 0; ni < 4; ++ni) bfr[ni] = *(const short8*)&Bs[(wc + ni * 16 + lm) * 32 + lk];
#pragma unroll
    for (int mi = 0; mi < 4; ++mi)
#pragma unroll
      for (int ni = 0; ni < 4; ++ni) acc[mi][ni] = MFMA16(af[mi], bfr[ni], acc[mi][ni]);
    __syncthreads();
  }

  const int row0 = bm * 128 + wr + (lane >> 4) * 4;
  const int col0 = bn * 128 + wc + lm;
#pragma unroll
  for (int mi = 0; mi < 4; ++mi) {
#pragma unroll
    for (int ni = 0; ni < 4; ++ni) {
      int col = col0 + ni * 16;
      float bia = BIAS ? bias[col] : 0.f;
#pragma unroll
      for (int rg = 0; rg < 4; ++rg) {
        int row = row0 + mi * 16 + rg;
        float vv = acc[mi][ni][rg] + bia;
        if (RELU) vv = vv > 0.f ? vv : 0.f;
        if (OUT_BF16)
          ((unsigned short*)Cp)[(size_t)row * Ndim + col] = f2bf(vv);
        else
          ((float*)Cp)[(size_t)row * Ndim + col] = vv;
      }
    }
  }
}

// ---- LN kernels: one wave per 768-wide row, 4 rows per block ----
__global__ __launch_bounds__(256) void ln0_k(const unsigned short* __restrict__ x,
                                             const float* __restrict__ g,
                                             const float* __restrict__ bb,
                                             unsigned short* __restrict__ out) {
  int w = threadIdx.x >> 6, lane = threadIdx.x & 63;
  long row = (long)blockIdx.x * 4 + w;
  const unsigned short* xr = x + row * HIDD;
  float xv[12];
  float s1 = 0.f, s2 = 0.f;
#pragma unroll
  for (int c = 0; c < 3; ++c) {
    us4 u = *(const us4*)(xr + c * 256 + lane * 4);
#pragma unroll
    for (int j = 0; j < 4; ++j) {
      float f = bf2f(u[j]);
      xv[c * 4 + j] = f; s1 += f; s2 += f * f;
    }
  }
#pragma unroll
  for (int off = 32; off; off >>= 1) { s1 += __shfl_xor(s1, off); s2 += __shfl_xor(s2, off); }
  float m = s1 * (1.f / 768.f);
  float rs = rsqrtf(s2 * (1.f / 768.f) - m * m + 1e-5f);
#pragma unroll
  for (int c = 0; c < 3; ++c) {
    int cb = c * 256 + lane * 4;
    us4 o;
#pragma unroll
    for (int j = 0; j < 4; ++j) o[j] = f2bf((xv[c * 4 + j] - m) * rs * g[cb + j] + bb[cb + j]);
    *(us4*)(out + row * HIDD + cb) = o;
  }
}

// ln1: h2 = hp(bf16) + LN(ctx bf16); writes h2 fp32 + h2 bf16
__global__ __launch_bounds__(256) void ln1_k(const unsigned short* __restrict__ ctx,
                                             const unsigned short* __restrict__ hp,
                                             const float* __restrict__ g,
                                             const float* __restrict__ bb,
                                             float* __restrict__ h2f,
                                             unsigned short* __restrict__ h2b) {
  int w = threadIdx.x >> 6, lane = threadIdx.x & 63;
  long row = (long)blockIdx.x * 4 + w;
  const unsigned short* xr = ctx + row * HIDD;
  float xv[12];
  float s1 = 0.f, s2 = 0.f;
#pragma unroll
  for (int c = 0; c < 3; ++c) {
    us4 u = *(const us4*)(xr + c * 256 + lane * 4);
#pragma unroll
    for (int j = 0; j < 4; ++j) {
      float f = bf2f(u[j]);
      xv[c * 4 + j] = f; s1 += f; s2 += f * f;
    }
  }
#pragma unroll
  for (int off = 32; off; off >>= 1) { s1 += __shfl_xor(s1, off); s2 += __shfl_xor(s2, off); }
  float m = s1 * (1.f / 768.f);
  float rs = rsqrtf(s2 * (1.f / 768.f) - m * m + 1e-5f);
#pragma unroll
  for (int c = 0; c < 3; ++c) {
    int cb = c * 256 + lane * 4;
    us4 hv = *(const us4*)(hp + row * HIDD + cb);
    fl4 o;
    us4 ob;
#pragma unroll
    for (int j = 0; j < 4; ++j) {
      float y = bf2f(hv[j]) + (xv[c * 4 + j] - m) * rs * g[cb + j] + bb[cb + j];
      o[j] = y; ob[j] = f2bf(y);
    }
    *(fl4*)(h2f + row * HIDD + cb) = o;
    *(us4*)(h2b + row * HIDD + cb) = ob;
  }
}

// ln2: out = h2f + LN(mlp2); mlp2 lives in d_out, in-place per-row
__global__ __launch_bounds__(256) void ln2_k(float* __restrict__ mlp2_out,
                                             const float* __restrict__ h2f,
                                             const float* __restrict__ g,
                                             const float* __restrict__ bb) {
  int w = threadIdx.x >> 6, lane = threadIdx.x & 63;
  long row = (long)blockIdx.x * 4 + w;
  float* xr = mlp2_out + row * HIDD;
  fl4 v[3];
  float s1 = 0.f, s2 = 0.f;
#pragma unroll
  for (int c = 0; c < 3; ++c) {
    v[c] = *(const fl4*)(xr + c * 256 + lane * 4);
#pragma unroll
    for (int j = 0; j < 4; ++j) { s1 += v[c][j]; s2 += v[c][j] * v[c][j]; }
  }
#pragma unroll
  for (int off = 32; off; off >>= 1) { s1 += __shfl_xor(s1, off); s2 += __shfl_xor(s2, off); }
  float m = s1 * (1.f / 768.f);
  float rs = rsqrtf(s2 * (1.f / 768.f) - m * m + 1e-5f);
#pragma unroll
  for (int c = 0; c < 3; ++c) {
    int cb = c * 256 + lane * 4;
    fl4 hv = *(const fl4*)(h2f + row * HIDD + cb);
    fl4 o;
#pragma unroll
    for (int j = 0; j < 4; ++j) o[j] = hv[j] + (v[c][j] - m) * rs * g[cb + j] + bb[cb + j];
    *(fl4*)(xr + cb) = o;
  }
}

// ---- fused attention over interleaved qkv[tok][2304] ----
// One block per (b, head). K staged in LDS (XOR-swizzled 128B rows), V^T in LDS.
__global__ __launch_bounds__(256, 2) void attn_k(const unsigned short* __restrict__ qkv,
                                                 unsigned short* __restrict__ ctx) {
  __shared__ __align__(16) unsigned short Ks[NPAT * 64];    // 25088 B, swizzled
  __shared__ __align__(16) unsigned short VT[64 * 232];     // 29696 B, V^T stride 232
  __shared__ __align__(16) unsigned short PL[4][16 * 40];   // 5120 B, per-wave P chunk
  const int b = blockIdx.x / NHEAD, h = blockIdx.x % NHEAD;
  const int t = threadIdx.x, lane = t & 63, w = t >> 6;
  const size_t base = ((size_t)b * NPAT) * QKVS + h * HDIM;   // q base; +768 = k, +1536 = v

  // stage K: row-major [196][64] bf16, 8x16B slots per row, slot ^= row&7
  for (int idx = t; idx < NPAT * 8; idx += 256) {
    int row = idx >> 3, s = idx & 7;
    us8 kv = *(const us8*)&qkv[base + 768 + (size_t)row * QKVS + s * 8];
    *(us8*)((char*)Ks + row * 128 + ((s ^ (row & 7)) << 4)) = kv;
  }
  // stage V^T: pack 2 consecutive patches per u32 write
  for (int idx = t; idx < 98 * 64; idx += 256) {
    int pp = idx >> 6, d = idx & 63;
    unsigned int val = (unsigned int)qkv[base + 1536 + (size_t)(2 * pp) * QKVS + d]
                     | ((unsigned int)qkv[base + 1536 + (size_t)(2 * pp + 1) * QKVS + d] << 16);
    *(unsigned int*)&VT[d * 232 + 2 * pp] = val;
  }
  for (int idx = t; idx < 64 * 18; idx += 256) {
    int d = idx / 18, c = idx % 18;
    *(unsigned int*)&VT[d * 232 + 196 + 2 * c] = 0;
  }
  __syncthreads();

  unsigned short* plw = (unsigned short*)PL[w];
  const int lm = lane & 15, lg = lane >> 4, lk = lg * 8;

  for (int qt = w; qt < 13; qt += 4) {
    const int q0 = qt * 16;
    int qrow = q0 + lm; if (qrow > NPAT - 1) qrow = NPAT - 1;
    short8 af0 = *(const short8*)&qkv[base + (size_t)qrow * QKVS + lk];
    short8 af1 = *(const short8*)&qkv[base + (size_t)qrow * QKVS + 32 + lk];

    f32x4 sc[13];
#pragma unroll
    for (int kt = 0; kt < 13; ++kt) {
      int krow = kt * 16 + lm; if (krow > NPAT - 1) krow = NPAT - 1;
      const char* krp = (const char*)Ks + krow * 128;
      short8 b0 = *(const short8*)(krp + (((lg ^ (krow & 7)) & 7) << 4));
      short8 b1 = *(const short8*)(krp + ((((lg + 4) ^ (krow & 7)) & 7) << 4));
      f32x4 z = (f32x4){0.f, 0.f, 0.f, 0.f};
      z = MFMA16(af0, b0, z);
      sc[kt] = MFMA16(af1, b1, z);
    }
#pragma unroll
    for (int kt = 0; kt < 13; ++kt) {
      int col = kt * 16 + lm;
#pragma unroll
      for (int rg = 0; rg < 4; ++rg) {
        float s = sc[kt][rg] * 0.125f;
        sc[kt][rg] = (col < NPAT) ? s : -1e30f;
      }
    }
    float inv[4];
#pragma unroll
    for (int rg = 0; rg < 4; ++rg) {
      float m = -1e30f;
#pragma unroll
      for (int kt = 0; kt < 13; ++kt) m = fmaxf(m, sc[kt][rg]);
      m = fmaxf(m, __shfl_xor(m, 1)); m = fmaxf(m, __shfl_xor(m, 2));
      m = fmaxf(m, __shfl_xor(m, 4)); m = fmaxf(m, __shfl_xor(m, 8));
      float s = 0.f;
#pragma unroll
      for (int kt = 0; kt < 13; ++kt) { float e = __expf(sc[kt][rg] - m); sc[kt][rg] = e; s += e; }
      s += __shfl_xor(s, 1); s += __shfl_xor(s, 2); s += __shfl_xor(s, 4); s += __shfl_xor(s, 8);
      inv[rg] = 1.f / s;
    }

    f32x4 oacc[4];
#pragma unroll
    for (int ni = 0; ni < 4; ++ni) oacc[ni] = (f32x4){0.f, 0.f, 0.f, 0.f};
#pragma unroll
    for (int kc = 0; kc < 7; ++kc) {
#pragma unroll
      for (int sub = 0; sub < 2; ++sub) {
        const int kt = 2 * kc + sub;
#pragma unroll
        for (int rg = 0; rg < 4; ++rg) {
          unsigned short pv_ = 0;
          if (kt < 13) pv_ = f2bf(sc[kt][rg] * inv[rg]);
          plw[(lg * 4 + rg) * 40 + sub * 16 + lm] = pv_;
        }
      }
      asm volatile("s_waitcnt lgkmcnt(0)" ::: "memory");
      __builtin_amdgcn_sched_barrier(0);
      short8 pa = *(const short8*)&plw[lm * 40 + lk];
#pragma unroll
      for (int ni = 0; ni < 4; ++ni) {
        short8 bv = *(const short8*)&VT[(ni * 16 + lm) * 232 + kc * 32 + lk];
        oacc[ni] = MFMA16(pa, bv, oacc[ni]);
      }
    }
#pragma unroll
    for (int rg = 0; rg < 4; ++rg) {
      int r = q0 + lg * 4 + rg;
      if (r < NPAT) {
#pragma unroll
        for (int ni = 0; ni < 4; ++ni)
          ctx[((size_t)b * NPAT + r) * HIDD + h * HDIM + ni * 16 + lm] = f2bf(oacc[ni][rg]);
      }
    }
  }
}

extern "C" void kernel_launch(void* const* d_in, const int* in_sizes, int n_in,
                              void* d_out, int out_size, void* d_ws, size_t ws_size,
                              hipStream_t stream) {
  const float* x    = (const float*)d_in[0];
  const float* q_w  = (const float*)d_in[1];
  const float* q_b  = (const float*)d_in[2];
  const float* k_w  = (const float*)d_in[3];
  const float* k_b  = (const float*)d_in[4];
  const float* v_w  = (const float*)d_in[5];
  const float* v_b  = (const float*)d_in[6];
  const float* w1   = (const float*)d_in[7];
  const float* b1   = (const float*)d_in[8];
  const float* w2   = (const float*)d_in[9];
  const float* b2   = (const float*)d_in[10];
  const float* ln0g = (const float*)d_in[11];
  const float* ln0b = (const float*)d_in[12];
  const float* ln1g = (const float*)d_in[13];
  const float* ln1b = (const float*)d_in[14];
  const float* ln2g = (const float*)d_in[15];
  const float* ln2b = (const float*)d_in[16];

  char* ws = (char*)d_ws;
  size_t o = 0;
  auto alloc = [&](size_t bytes) { size_t r = o; o += (bytes + 255) & ~(size_t)255; return r; };

  const size_t RSZ = (size_t)NTOK * HIDD * 2;   // 38,535,168 B per region (256-aligned)
  unsigned short* Mb    = (unsigned short*)(ws + alloc(256 * 256 * 2));
  unsigned short* wqkvb = (unsigned short*)(ws + alloc((size_t)QKVS * HIDD * 2));
  unsigned short* w1b   = (unsigned short*)(ws + alloc((size_t)FFD * HIDD * 2));
  unsigned short* w2b   = (unsigned short*)(ws + alloc((size_t)HIDD * FFD * 2));
  float*          qkvbias = (float*)(ws + alloc(QKVS * 4));
  char* r0 = ws + alloc(RSZ);   // x bf16 -> ctx -> mlp1 chunk (low half)
  char* r1 = ws + alloc(RSZ);   // hp bf16 -> mlp1 chunk (high half); r0+r1 contiguous
  char* r2 = ws + alloc(RSZ);   // hb (ln0 out) -> h2 bf16
  char* r3 = ws + alloc(RSZ);   // qkv interleaved (low third)
  char* r4 = ws + alloc(RSZ);   // qkv mid   -> h2 fp32 (low half)
  char* r5 = ws + alloc(RSZ);   // qkv high  -> h2 fp32 (high half); r4+r5 contiguous
  (void)r5; (void)n_in; (void)in_sizes; (void)ws_size;

  unsigned short* xb  = (unsigned short*)r0;
  unsigned short* hpb = (unsigned short*)r1;
  unsigned short* hb  = (unsigned short*)r2;
  unsigned short* qkv = (unsigned short*)r3;   // [25088][2304] spans r3+r4+r5 exactly
  unsigned short* cxb = (unsigned short*)r0;   // ctx (x dead after highpass)
  float*          h2f = (float*)r4;            // 77MB spans r4+r5 (qkv dead after attn)
  unsigned short* h2b = (unsigned short*)r2;   // hb dead after QKV
  unsigned short* m1b = (unsigned short*)r0;   // mlp1 chunk spans r0+r1 (77,070,336 B)
  float*          m2f = (float*)d_out;         // mlp2 fp32 straight into d_out

  build_M<<<1, 256, 0, stream>>>(Mb);
  bias_cat<<<1, 256, 0, stream>>>(q_b, k_b, v_b, qkvbias);

  auto cgrid = [](long n4) { long g = (n4 + 255) / 256; return (int)(g > 2048 ? 2048 : g); };
  long nx4 = (long)NTOK * HIDD / 4;
  castk<<<cgrid(nx4), 256, 0, stream>>>(x, xb, nx4);
  long nw4 = (long)HIDD * HIDD / 4;
  castk<<<cgrid(nw4), 256, 0, stream>>>(q_w, wqkvb, nw4);
  castk<<<cgrid(nw4), 256, 0, stream>>>(k_w, wqkvb + (size_t)768 * HIDD, nw4);
  castk<<<cgrid(nw4), 256, 0, stream>>>(v_w, wqkvb + (size_t)1536 * HIDD, nw4);
  long nf4 = (long)FFD * HIDD / 4;
  castk<<<cgrid(nf4), 256, 0, stream>>>(w1, w1b, nf4);
  castk<<<cgrid(nf4), 256, 0, stream>>>(w2, w2b, nf4);

  // highpass: (75264 x 256) @ M(256 x 256)^T -> hp bf16
  gemm_bt<1, 0, 0><<<588 * 2, 256, 0, stream>>>(xb, Mb, nullptr, hpb, 75264, 256, 256);
  ln0_k<<<NTOK / 4, 256, 0, stream>>>(hpb, ln0g, ln0b, hb);

  // fused QKV: (25088 x 768) @ (2304 x 768)^T -> qkv interleaved
  gemm_bt<1, 1, 0><<<196 * 18, 256, 0, stream>>>(hb, wqkvb, qkvbias, qkv, NTOK, QKVS, HIDD);

  attn_k<<<128 * NHEAD, 256, 0, stream>>>(qkv, cxb);

  ln1_k<<<NTOK / 4, 256, 0, stream>>>(cxb, hpb, ln1g, ln1b, h2f, h2b);

  // MLP in 2 token-chunks of 12544 (=98*128); mlp1 chunk fills r0+r1 exactly
  for (int ch = 0; ch < 2; ++ch) {
    const unsigned short* h2c = h2b + (size_t)ch * 12544 * HIDD;
    float* m2c = m2f + (size_t)ch * 12544 * HIDD;
    gemm_bt<1, 1, 1><<<98 * 24, 256, 0, stream>>>(h2c, w1b, b1, m1b, 12544, FFD, HIDD);
    gemm_bt<0, 1, 0><<<98 * 6, 256, 0, stream>>>(m1b, w2b, b2, m2c, 12544, HIDD, FFD);
  }

  // final: d_out = h2f + LN(d_out), in-place per row
  ln2_k<<<NTOK / 4, 256, 0, stream>>>(m2f, h2f, ln2g, ln2b);
  (void)out_size;
}

// Round 6
// 716.952 us; speedup vs baseline: 1.3416x; 1.0620x over previous
//
#include <hip/hip_runtime.h>

#define NTOK   25088          // B*P = 128*196
#define HIDD   768
#define NHEAD  12
#define HDIM   64
#define FFD    3072
#define NPAT   196
#define QKVS   2304           // interleaved qkv row stride

typedef __attribute__((ext_vector_type(8))) short short8;
typedef __attribute__((ext_vector_type(8))) __bf16 bf16x8;
typedef __attribute__((ext_vector_type(4))) float f32x4;
typedef __attribute__((ext_vector_type(4))) float fl4;
typedef __attribute__((ext_vector_type(4))) unsigned short us4;
typedef __attribute__((ext_vector_type(8))) unsigned short us8;

#define AS1 __attribute__((address_space(1)))
#define AS3 __attribute__((address_space(3)))

__device__ __forceinline__ unsigned short f2bf(float f) {
  unsigned int u = __builtin_bit_cast(unsigned int, f);
  u += 0x7FFFu + ((u >> 16) & 1u);
  return (unsigned short)(u >> 16);
}
__device__ __forceinline__ float bf2f(unsigned short h) {
  unsigned int u = ((unsigned int)h) << 16;
  return __builtin_bit_cast(float, u);
}

// ---- MFMA wrapper: SFINAE over builtin operand type (short8 vs bf16x8) ----
template <typename A>
__device__ __forceinline__ auto mfma_sel(A a, A b, f32x4 c, int)
    -> decltype(__builtin_amdgcn_mfma_f32_16x16x32_bf16(a, b, c, 0, 0, 0)) {
  return __builtin_amdgcn_mfma_f32_16x16x32_bf16(a, b, c, 0, 0, 0);
}
template <typename A>
__device__ __forceinline__ auto mfma_sel(A a, A b, f32x4 c, long)
    -> decltype(__builtin_amdgcn_mfma_f32_16x16x32_bf16(
           __builtin_bit_cast(bf16x8, a), __builtin_bit_cast(bf16x8, b), c, 0, 0, 0)) {
  return __builtin_amdgcn_mfma_f32_16x16x32_bf16(
      __builtin_bit_cast(bf16x8, a), __builtin_bit_cast(bf16x8, b), c, 0, 0, 0);
}
__device__ __forceinline__ f32x4 MFMA16(short8 a, short8 b, f32x4 c) {
  return mfma_sel(a, b, c, 0);
}

__device__ __forceinline__ void gload16(const void* g, void* l) {
  __builtin_amdgcn_global_load_lds((const AS1 void*)g, (AS3 void*)l, 16, 0, 0);
}

// T1: bijective XCD-aware block swizzle (m204). HW maps orig%8 -> XCD; this
// gives each XCD a contiguous bn-major chunk so blocks sharing an A-panel
// stay in one L2.
__device__ __forceinline__ int swz_bid(int nwg) {
  int orig = (int)blockIdx.x;
  int xcd = orig & 7;
  int q = nwg >> 3, r = nwg & 7;
  int base = (xcd < r) ? xcd * (q + 1) : r * (q + 1) + (xcd - r) * q;
  return base + (orig >> 3);
}

// ---- build the 256x256 highpass operator, bf16, symmetric ----
__global__ __launch_bounds__(256) void build_M(unsigned short* __restrict__ Mb) {
  __shared__ float Cs[16], Ss[16];
  int t = threadIdx.x;
  if (t < 16) {
    float c = 0.f;
    for (int k = -4; k <= 3; ++k) c += cosf(0.39269908169872414f * (float)(k * t));
    Cs[t] = c;
    Ss[t] = -sinf(1.5707963267948966f * (float)t);
  }
  __syncthreads();
  int r = t >> 4, cc = t & 15;
  for (int j = 0; j < 256; ++j) {
    int dr = (r - (j >> 4)) & 15;
    int dc = (cc - (j & 15)) & 15;
    float val = ((t == j) ? 1.f : 0.f) - (Cs[dr] * Cs[dc] - Ss[dr] * Ss[dc]) * 0.00390625f;
    Mb[t * 256 + j] = f2bf(val);
  }
}

// ---- fp32 -> bf16 cast (element count multiple of 4) ----
__global__ __launch_bounds__(256) void castk(const float* __restrict__ s,
                                             unsigned short* __restrict__ d, long n4) {
  for (long i = (long)blockIdx.x * 256 + threadIdx.x; i < n4; i += (long)gridDim.x * 256) {
    fl4 v = *(const fl4*)(s + i * 4);
    us4 o;
    o[0] = f2bf(v[0]); o[1] = f2bf(v[1]); o[2] = f2bf(v[2]); o[3] = f2bf(v[3]);
    *(us4*)(d + i * 4) = o;
  }
}

// ---- concat q_b,k_b,v_b -> [2304] fp32 ----
__global__ __launch_bounds__(256) void bias_cat(const float* __restrict__ qb,
                                                const float* __restrict__ kb,
                                                const float* __restrict__ vb,
                                                float* __restrict__ d) {
  for (int i = threadIdx.x; i < QKVS; i += 256)
    d[i] = (i < 768) ? qb[i] : (i < 1536) ? kb[i - 768] : vb[i - 1536];
}

// ---- bf16 GEMM, C = A(MxK) * B(NxK)^T, m97-style 128x128 tile, BK=32 ----
template <int OUT_BF16, int BIAS, int RELU>
__global__ __launch_bounds__(256) void gemm_bt(const unsigned short* __restrict__ A,
                                               const unsigned short* __restrict__ Bm,
                                               const float* __restrict__ bias,
                                               void* __restrict__ Cp,
                                               int Mdim, int Ndim, int Kdim) {
  __shared__ __align__(16) unsigned short As[128 * 32];
  __shared__ __align__(16) unsigned short Bs[128 * 32];
  const int nbn = Ndim >> 7;
  const int bid = swz_bid((int)gridDim.x);
  const int bm = bid / nbn, bn = bid % nbn;
  const int t = threadIdx.x;
  const int lane = t & 63;
  const int w = t >> 6;
  const int wr = (w >> 1) * 64, wc = (w & 1) * 64;
  const int lm = lane & 15, lk = (lane >> 4) * 8;

  f32x4 acc[4][4];
#pragma unroll
  for (int i = 0; i < 4; ++i)
#pragma unroll
    for (int j = 0; j < 4; ++j) acc[i][j] = (f32x4){0.f, 0.f, 0.f, 0.f};

  const unsigned short* Ab = A + (size_t)(bm * 128 + (t >> 2)) * Kdim + (t & 3) * 8;
  const unsigned short* Bb = Bm + (size_t)(bn * 128 + (t >> 2)) * Kdim + (t & 3) * 8;
  unsigned short* AsP = As + t * 8;
  unsigned short* BsP = Bs + t * 8;

  for (int k0 = 0; k0 < Kdim; k0 += 32) {
    gload16(Ab + k0, AsP);
    gload16(Ab + (size_t)64 * Kdim + k0, AsP + 2048);
    gload16(Bb + k0, BsP);
    gload16(Bb + (size_t)64 * Kdim + k0, BsP + 2048);
    asm volatile("s_waitcnt vmcnt(0)" ::: "memory");
    __syncthreads();
    short8 af[4], bfr[4];
#pragma unroll
    for (int mi = 0; mi < 4; ++mi) af[mi] = *(const short8*)&As[(wr + mi * 16 + lm) * 32 + lk];
#pragma unroll
    for (int ni = 0; ni < 4; ++ni) bfr[ni] = *(const short8*)&Bs[(wc + ni * 16 + lm) * 32 + lk];
#pragma unroll
    for (int mi = 0; mi < 4; ++mi)
#pragma unroll
      for (int ni = 0; ni < 4; ++ni) acc[mi][ni] = MFMA16(af[mi], bfr[ni], acc[mi][ni]);
    __syncthreads();
  }

  const int row0 = bm * 128 + wr + (lane >> 4) * 4;
  const int col0 = bn * 128 + wc + lm;
#pragma unroll
  for (int mi = 0; mi < 4; ++mi) {
#pragma unroll
    for (int ni = 0; ni < 4; ++ni) {
      int col = col0 + ni * 16;
      float bia = BIAS ? bias[col] : 0.f;
#pragma unroll
      for (int rg = 0; rg < 4; ++rg) {
        int row = row0 + mi * 16 + rg;
        float vv = acc[mi][ni][rg] + bia;
        if (RELU) vv = vv > 0.f ? vv : 0.f;
        if (OUT_BF16)
          ((unsigned short*)Cp)[(size_t)row * Ndim + col] = f2bf(vv);
        else
          ((float*)Cp)[(size_t)row * Ndim + col] = vv;
      }
    }
  }
}

// ---- LN kernels: one wave per 768-wide row, 4 rows per block ----
__global__ __launch_bounds__(256) void ln0_k(const unsigned short* __restrict__ x,
                                             const float* __restrict__ g,
                                             const float* __restrict__ bb,
                                             unsigned short* __restrict__ out) {
  int w = threadIdx.x >> 6, lane = threadIdx.x & 63;
  long row = (long)blockIdx.x * 4 + w;
  const unsigned short* xr = x + row * HIDD;
  float xv[12];
  float s1 = 0.f, s2 = 0.f;
#pragma unroll
  for (int c = 0; c < 3; ++c) {
    us4 u = *(const us4*)(xr + c * 256 + lane * 4);
#pragma unroll
    for (int j = 0; j < 4; ++j) {
      float f = bf2f(u[j]);
      xv[c * 4 + j] = f; s1 += f; s2 += f * f;
    }
  }
#pragma unroll
  for (int off = 32; off; off >>= 1) { s1 += __shfl_xor(s1, off); s2 += __shfl_xor(s2, off); }
  float m = s1 * (1.f / 768.f);
  float rs = rsqrtf(s2 * (1.f / 768.f) - m * m + 1e-5f);
#pragma unroll
  for (int c = 0; c < 3; ++c) {
    int cb = c * 256 + lane * 4;
    us4 o;
#pragma unroll
    for (int j = 0; j < 4; ++j) o[j] = f2bf((xv[c * 4 + j] - m) * rs * g[cb + j] + bb[cb + j]);
    *(us4*)(out + row * HIDD + cb) = o;
  }
}

// ln1: h2 = hp(bf16) + LN(ctx bf16); writes h2 fp32 + h2 bf16
__global__ __launch_bounds__(256) void ln1_k(const unsigned short* __restrict__ ctx,
                                             const unsigned short* __restrict__ hp,
                                             const float* __restrict__ g,
                                             const float* __restrict__ bb,
                                             float* __restrict__ h2f,
                                             unsigned short* __restrict__ h2b) {
  int w = threadIdx.x >> 6, lane = threadIdx.x & 63;
  long row = (long)blockIdx.x * 4 + w;
  const unsigned short* xr = ctx + row * HIDD;
  float xv[12];
  float s1 = 0.f, s2 = 0.f;
#pragma unroll
  for (int c = 0; c < 3; ++c) {
    us4 u = *(const us4*)(xr + c * 256 + lane * 4);
#pragma unroll
    for (int j = 0; j < 4; ++j) {
      float f = bf2f(u[j]);
      xv[c * 4 + j] = f; s1 += f; s2 += f * f;
    }
  }
#pragma unroll
  for (int off = 32; off; off >>= 1) { s1 += __shfl_xor(s1, off); s2 += __shfl_xor(s2, off); }
  float m = s1 * (1.f / 768.f);
  float rs = rsqrtf(s2 * (1.f / 768.f) - m * m + 1e-5f);
#pragma unroll
  for (int c = 0; c < 3; ++c) {
    int cb = c * 256 + lane * 4;
    us4 hv = *(const us4*)(hp + row * HIDD + cb);
    fl4 o;
    us4 ob;
#pragma unroll
    for (int j = 0; j < 4; ++j) {
      float y = bf2f(hv[j]) + (xv[c * 4 + j] - m) * rs * g[cb + j] + bb[cb + j];
      o[j] = y; ob[j] = f2bf(y);
    }
    *(fl4*)(h2f + row * HIDD + cb) = o;
    *(us4*)(h2b + row * HIDD + cb) = ob;
  }
}

// ln2: out = h2f + LN(mlp2); mlp2 lives in d_out, in-place per-row
__global__ __launch_bounds__(256) void ln2_k(float* __restrict__ mlp2_out,
                                             const float* __restrict__ h2f,
                                             const float* __restrict__ g,
                                             const float* __restrict__ bb) {
  int w = threadIdx.x >> 6, lane = threadIdx.x & 63;
  long row = (long)blockIdx.x * 4 + w;
  float* xr = mlp2_out + row * HIDD;
  fl4 v[3];
  float s1 = 0.f, s2 = 0.f;
#pragma unroll
  for (int c = 0; c < 3; ++c) {
    v[c] = *(const fl4*)(xr + c * 256 + lane * 4);
#pragma unroll
    for (int j = 0; j < 4; ++j) { s1 += v[c][j]; s2 += v[c][j] * v[c][j]; }
  }
#pragma unroll
  for (int off = 32; off; off >>= 1) { s1 += __shfl_xor(s1, off); s2 += __shfl_xor(s2, off); }
  float m = s1 * (1.f / 768.f);
  float rs = rsqrtf(s2 * (1.f / 768.f) - m * m + 1e-5f);
#pragma unroll
  for (int c = 0; c < 3; ++c) {
    int cb = c * 256 + lane * 4;
    fl4 hv = *(const fl4*)(h2f + row * HIDD + cb);
    fl4 o;
#pragma unroll
    for (int j = 0; j < 4; ++j) o[j] = hv[j] + (v[c][j] - m) * rs * g[cb + j] + bb[cb + j];
    *(fl4*)(xr + cb) = o;
  }
}

// ---- fused attention over interleaved qkv[tok][2304] ----
// One block per (b, head). K staged in LDS (XOR-swizzled 128B rows), V^T in LDS.
__global__ __launch_bounds__(256, 2) void attn_k(const unsigned short* __restrict__ qkv,
                                                 unsigned short* __restrict__ ctx) {
  __shared__ __align__(16) unsigned short Ks[NPAT * 64];    // 25088 B, swizzled
  __shared__ __align__(16) unsigned short VT[64 * 232];     // 29696 B, V^T stride 232
  __shared__ __align__(16) unsigned short PL[4][16 * 40];   // 5120 B, per-wave P chunk
  const int b = blockIdx.x / NHEAD, h = blockIdx.x % NHEAD;
  const int t = threadIdx.x, lane = t & 63, w = t >> 6;
  const size_t base = ((size_t)b * NPAT) * QKVS + h * HDIM;   // q base; +768 = k, +1536 = v

  // stage K: row-major [196][64] bf16, 8x16B slots per row, slot ^= row&7
  for (int idx = t; idx < NPAT * 8; idx += 256) {
    int row = idx >> 3, s = idx & 7;
    us8 kv = *(const us8*)&qkv[base + 768 + (size_t)row * QKVS + s * 8];
    *(us8*)((char*)Ks + row * 128 + ((s ^ (row & 7)) << 4)) = kv;
  }
  // stage V^T: pack 2 consecutive patches per u32 write
  for (int idx = t; idx < 98 * 64; idx += 256) {
    int pp = idx >> 6, d = idx & 63;
    unsigned int val = (unsigned int)qkv[base + 1536 + (size_t)(2 * pp) * QKVS + d]
                     | ((unsigned int)qkv[base + 1536 + (size_t)(2 * pp + 1) * QKVS + d] << 16);
    *(unsigned int*)&VT[d * 232 + 2 * pp] = val;
  }
  for (int idx = t; idx < 64 * 18; idx += 256) {
    int d = idx / 18, c = idx % 18;
    *(unsigned int*)&VT[d * 232 + 196 + 2 * c] = 0;
  }
  __syncthreads();

  unsigned short* plw = (unsigned short*)PL[w];
  const int lm = lane & 15, lg = lane >> 4, lk = lg * 8;

  for (int qt = w; qt < 13; qt += 4) {
    const int q0 = qt * 16;
    int qrow = q0 + lm; if (qrow > NPAT - 1) qrow = NPAT - 1;
    short8 af0 = *(const short8*)&qkv[base + (size_t)qrow * QKVS + lk];
    short8 af1 = *(const short8*)&qkv[base + (size_t)qrow * QKVS + 32 + lk];

    f32x4 sc[13];
#pragma unroll
    for (int kt = 0; kt < 13; ++kt) {
      int krow = kt * 16 + lm; if (krow > NPAT - 1) krow = NPAT - 1;
      const char* krp = (const char*)Ks + krow * 128;
      short8 b0 = *(const short8*)(krp + (((lg ^ (krow & 7)) & 7) << 4));
      short8 b1 = *(const short8*)(krp + ((((lg + 4) ^ (krow & 7)) & 7) << 4));
      f32x4 z = (f32x4){0.f, 0.f, 0.f, 0.f};
      z = MFMA16(af0, b0, z);
      sc[kt] = MFMA16(af1, b1, z);
    }
#pragma unroll
    for (int kt = 0; kt < 13; ++kt) {
      int col = kt * 16 + lm;
#pragma unroll
      for (int rg = 0; rg < 4; ++rg) {
        float s = sc[kt][rg] * 0.125f;
        sc[kt][rg] = (col < NPAT) ? s : -1e30f;
      }
    }
    float inv[4];
#pragma unroll
    for (int rg = 0; rg < 4; ++rg) {
      float m = -1e30f;
#pragma unroll
      for (int kt = 0; kt < 13; ++kt) m = fmaxf(m, sc[kt][rg]);
      m = fmaxf(m, __shfl_xor(m, 1)); m = fmaxf(m, __shfl_xor(m, 2));
      m = fmaxf(m, __shfl_xor(m, 4)); m = fmaxf(m, __shfl_xor(m, 8));
      float s = 0.f;
#pragma unroll
      for (int kt = 0; kt < 13; ++kt) { float e = __expf(sc[kt][rg] - m); sc[kt][rg] = e; s += e; }
      s += __shfl_xor(s, 1); s += __shfl_xor(s, 2); s += __shfl_xor(s, 4); s += __shfl_xor(s, 8);
      inv[rg] = 1.f / s;
    }

    f32x4 oacc[4];
#pragma unroll
    for (int ni = 0; ni < 4; ++ni) oacc[ni] = (f32x4){0.f, 0.f, 0.f, 0.f};
#pragma unroll
    for (int kc = 0; kc < 7; ++kc) {
#pragma unroll
      for (int sub = 0; sub < 2; ++sub) {
        const int kt = 2 * kc + sub;
#pragma unroll
        for (int rg = 0; rg < 4; ++rg) {
          unsigned short pv_ = 0;
          if (kt < 13) pv_ = f2bf(sc[kt][rg] * inv[rg]);
          plw[(lg * 4 + rg) * 40 + sub * 16 + lm] = pv_;
        }
      }
      asm volatile("s_waitcnt lgkmcnt(0)" ::: "memory");
      __builtin_amdgcn_sched_barrier(0);
      short8 pa = *(const short8*)&plw[lm * 40 + lk];
#pragma unroll
      for (int ni = 0; ni < 4; ++ni) {
        short8 bv = *(const short8*)&VT[(ni * 16 + lm) * 232 + kc * 32 + lk];
        oacc[ni] = MFMA16(pa, bv, oacc[ni]);
      }
    }
#pragma unroll
    for (int rg = 0; rg < 4; ++rg) {
      int r = q0 + lg * 4 + rg;
      if (r < NPAT) {
#pragma unroll
        for (int ni = 0; ni < 4; ++ni)
          ctx[((size_t)b * NPAT + r) * HIDD + h * HDIM + ni * 16 + lm] = f2bf(oacc[ni][rg]);
      }
    }
  }
}

extern "C" void kernel_launch(void* const* d_in, const int* in_sizes, int n_in,
                              void* d_out, int out_size, void* d_ws, size_t ws_size,
                              hipStream_t stream) {
  const float* x    = (const float*)d_in[0];
  const float* q_w  = (const float*)d_in[1];
  const float* q_b  = (const float*)d_in[2];
  const float* k_w  = (const float*)d_in[3];
  const float* k_b  = (const float*)d_in[4];
  const float* v_w  = (const float*)d_in[5];
  const float* v_b  = (const float*)d_in[6];
  const float* w1   = (const float*)d_in[7];
  const float* b1   = (const float*)d_in[8];
  const float* w2   = (const float*)d_in[9];
  const float* b2   = (const float*)d_in[10];
  const float* ln0g = (const float*)d_in[11];
  const float* ln0b = (const float*)d_in[12];
  const float* ln1g = (const float*)d_in[13];
  const float* ln1b = (const float*)d_in[14];
  const float* ln2g = (const float*)d_in[15];
  const float* ln2b = (const float*)d_in[16];

  char* ws = (char*)d_ws;
  size_t o = 0;
  auto alloc = [&](size_t bytes) { size_t r = o; o += (bytes + 255) & ~(size_t)255; return r; };

  const size_t RSZ = (size_t)NTOK * HIDD * 2;   // 38,535,168 B per region (256-aligned)
  unsigned short* Mb    = (unsigned short*)(ws + alloc(256 * 256 * 2));
  unsigned short* wqkvb = (unsigned short*)(ws + alloc((size_t)QKVS * HIDD * 2));
  unsigned short* w1b   = (unsigned short*)(ws + alloc((size_t)FFD * HIDD * 2));
  unsigned short* w2b   = (unsigned short*)(ws + alloc((size_t)HIDD * FFD * 2));
  float*          qkvbias = (float*)(ws + alloc(QKVS * 4));
  char* r0 = ws + alloc(RSZ);   // x bf16 -> ctx -> mlp1 chunk (low half)
  char* r1 = ws + alloc(RSZ);   // hp bf16 -> mlp1 chunk (high half); r0+r1 contiguous
  char* r2 = ws + alloc(RSZ);   // hb (ln0 out) -> h2 bf16
  char* r3 = ws + alloc(RSZ);   // qkv interleaved (low third)
  char* r4 = ws + alloc(RSZ);   // qkv mid   -> h2 fp32 (low half)
  char* r5 = ws + alloc(RSZ);   // qkv high  -> h2 fp32 (high half); r4+r5 contiguous
  (void)r5; (void)n_in; (void)in_sizes; (void)ws_size;

  unsigned short* xb  = (unsigned short*)r0;
  unsigned short* hpb = (unsigned short*)r1;
  unsigned short* hb  = (unsigned short*)r2;
  unsigned short* qkv = (unsigned short*)r3;   // [25088][2304] spans r3+r4+r5 exactly
  unsigned short* cxb = (unsigned short*)r0;   // ctx (x dead after highpass)
  float*          h2f = (float*)r4;            // 77MB spans r4+r5 (qkv dead after attn)
  unsigned short* h2b = (unsigned short*)r2;   // hb dead after QKV
  unsigned short* m1b = (unsigned short*)r0;   // mlp1 chunk spans r0+r1 (77,070,336 B)
  float*          m2f = (float*)d_out;         // mlp2 fp32 straight into d_out

  build_M<<<1, 256, 0, stream>>>(Mb);
  bias_cat<<<1, 256, 0, stream>>>(q_b, k_b, v_b, qkvbias);

  auto cgrid = [](long n4) { long g = (n4 + 255) / 256; return (int)(g > 2048 ? 2048 : g); };
  long nx4 = (long)NTOK * HIDD / 4;
  castk<<<cgrid(nx4), 256, 0, stream>>>(x, xb, nx4);
  long nw4 = (long)HIDD * HIDD / 4;
  castk<<<cgrid(nw4), 256, 0, stream>>>(q_w, wqkvb, nw4);
  castk<<<cgrid(nw4), 256, 0, stream>>>(k_w, wqkvb + (size_t)768 * HIDD, nw4);
  castk<<<cgrid(nw4), 256, 0, stream>>>(v_w, wqkvb + (size_t)1536 * HIDD, nw4);
  long nf4 = (long)FFD * HIDD / 4;
  castk<<<cgrid(nf4), 256, 0, stream>>>(w1, w1b, nf4);
  castk<<<cgrid(nf4), 256, 0, stream>>>(w2, w2b, nf4);

  // highpass: (75264 x 256) @ M(256 x 256)^T -> hp bf16
  gemm_bt<1, 0, 0><<<588 * 2, 256, 0, stream>>>(xb, Mb, nullptr, hpb, 75264, 256, 256);
  ln0_k<<<NTOK / 4, 256, 0, stream>>>(hpb, ln0g, ln0b, hb);

  // fused QKV: (25088 x 768) @ (2304 x 768)^T -> qkv interleaved
  gemm_bt<1, 1, 0><<<196 * 18, 256, 0, stream>>>(hb, wqkvb, qkvbias, qkv, NTOK, QKVS, HIDD);

  attn_k<<<128 * NHEAD, 256, 0, stream>>>(qkv, cxb);

  ln1_k<<<NTOK / 4, 256, 0, stream>>>(cxb, hpb, ln1g, ln1b, h2f, h2b);

  // MLP in 2 token-chunks of 12544 (=98*128); mlp1 chunk fills r0+r1 exactly
  for (int ch = 0; ch < 2; ++ch) {
    const unsigned short* h2c = h2b + (size_t)ch * 12544 * HIDD;
    float* m2c = m2f + (size_t)ch * 12544 * HIDD;
    gemm_bt<1, 1, 1><<<98 * 24, 256, 0, stream>>>(h2c, w1b, b1, m1b, 12544, FFD, HIDD);
    gemm_bt<0, 1, 0><<<98 * 6, 256, 0, stream>>>(m1b, w2b, b2, m2c, 12544, HIDD, FFD);
  }

  // final: d_out = h2f + LN(d_out), in-place per row
  ln2_k<<<NTOK / 4, 256, 0, stream>>>(m2f, h2f, ln2g, ln2b);
  (void)out_size;
}